// Round 5
// baseline (901.560 us; speedup 1.0000x reference)
//
#include <hip/hip_runtime.h>

#define BATCH 8
#define NN 32768
#define KK 128
#define NCHUNK 32
#define CHUNK 1024            // NN / NCHUNK
#define NST 16                // super-tiles of 64 n per chunk
#define NITER 8               // CG iterations

// ---- instrumentation: internal idempotent repeats (R5 measurement round) ----
#define REP_PREP  12
#define REP_GRAM  24
#define REP_RED   64
#define REP_SOLVE 32

typedef __attribute__((ext_vector_type(8)))  _Float16 half8;
typedef __attribute__((ext_vector_type(4)))  _Float16 half4;
typedef __attribute__((ext_vector_type(16))) float    f32x16;

// ---- workspace byte offsets (total ~15.2 MB) ----
#define MT_OFF   0ull                      // multT fp16 [128][32768]
#define WH_OFF   (MT_OFF + 8388608ull)     // wh fp16 [8][32768]  (mask)
#define DH_OFF   (WH_OFF + 524288ull)      // dh fp16 [8][32768]  (data)
#define GP_OFF   (DH_OFF + 524288ull)      // Gp fp16 [8][32][10][1024] partial tiles
#define MP_OFF   (GP_OFF + 5242880ull)     // Mp f32  [8][32][128]
#define G_OFF    (MP_OFF + 131072ull)      // G  f32  [8][128][128]

// ---------------------------------------------------------------------------
// K0: fused conv + transpose (identical work to R4, wrapped in REP_PREP).
// ---------------------------------------------------------------------------
__global__ __launch_bounds__(256) void prep_kernel(
    const float* __restrict__ data0, const float* __restrict__ mask0,
    const float* __restrict__ mult0, unsigned char* __restrict__ ws)
{
    __shared__ _Float16 t[128][136];
    const int tid = threadIdx.x;
    const int n0  = blockIdx.x * 128;

#pragma unroll 1
    for (int rep = 0; rep < REP_PREP; ++rep) {
        const float* data = data0;  asm volatile("" : "+v"(data));
        const float* mask = mask0;  asm volatile("" : "+v"(mask));
        const float* mult = mult0;  asm volatile("" : "+v"(mult));
        __syncthreads();            // LDS reuse fence across reps

        {
            const int b = tid >> 5, q = tid & 31;
            const size_t src = (size_t)b * NN + n0 + q * 4;
            const float4 d4 = *(const float4*)(data + src);
            const float4 m4 = *(const float4*)(mask + src);
            half4 w = { (_Float16)m4.x, (_Float16)m4.y, (_Float16)m4.z, (_Float16)m4.w };
            half4 d = { (_Float16)d4.x, (_Float16)d4.y, (_Float16)d4.z, (_Float16)d4.w };
            *(half4*)((_Float16*)(ws + WH_OFF) + src) = w;
            *(half4*)((_Float16*)(ws + DH_OFF) + src) = d;
        }

        const float4* m4p = (const float4*)mult;
#pragma unroll
        for (int u = 0; u < 16; ++u) {
            const int c16 = u * 256 + tid;
            const int n  = c16 >> 5;
            const int kq = c16 & 31;
            float4 v = m4p[(size_t)(n0 + n) * 32 + kq];
            half4 h = { (_Float16)v.x, (_Float16)v.y, (_Float16)v.z, (_Float16)v.w };
            const int c4s = kq ^ ((n >> 3) & 7);
            *(half4*)&t[n][c4s * 4] = h;
        }
        __syncthreads();

        _Float16* mt = (_Float16*)(ws + MT_OFF);
        const int g = tid & 15;
#pragma unroll
        for (int i = 0; i < 8; ++i) {
            const int k = (tid >> 4) + i * 16;
            half8 v;
#pragma unroll
            for (int j = 0; j < 8; ++j) {
                const int n = g * 8 + j;
                const int cs = (k >> 2) ^ ((n >> 3) & 7);
                v[j] = t[n][cs * 4 + (k & 3)];
            }
            *(half8*)(mt + (size_t)k * NN + n0 + g * 8) = v;
        }
    }
}

// ---------------------------------------------------------------------------
// K1: MFMA gram partials (identical work to R4, wrapped in REP_GRAM).
// ---------------------------------------------------------------------------
__global__ __launch_bounds__(256, 1) void gram_kernel(
    unsigned char* __restrict__ ws0)
{
    __shared__ unsigned char smem[36864];
    const int tid = threadIdx.x;
    const int b     = blockIdx.x >> 5;
    const int chunk = blockIdx.x & 31;
    const int n0    = chunk * CHUNK;
    const int w = tid >> 6, l = tid & 63;

#pragma unroll 1
    for (int rep = 0; rep < REP_GRAM; ++rep) {
        unsigned char* ws = ws0;  asm volatile("" : "+v"(ws));
        const _Float16* mt = (const _Float16*)(ws + MT_OFF);
        __syncthreads();          // LDS reuse fence across reps

        if (tid < 128) {
            half8 wv = *(const half8*)((const _Float16*)(ws + WH_OFF) + (size_t)b * NN + n0 + tid * 8);
            half8 dv = *(const half8*)((const _Float16*)(ws + DH_OFF) + (size_t)b * NN + n0 + tid * 8);
            *(half8*)(smem + 32768 + tid * 16) = wv;
            *(half8*)(smem + 34816 + tid * 16) = dv;
        }

        const int krow = tid >> 3;
        const int gd   = tid & 7;
        const _Float16* gsrc0 = mt + (size_t)krow * NN + n0 + gd * 8;
        const int wslot = (gd ^ (krow & 7)) * 16;

        uint4 S0, S1, S2, S3;
#define GLOAD(st_) { const _Float16* p = gsrc0 + (size_t)(st_) * 64;          \
        S0 = *(const uint4*)(p);                                              \
        S1 = *(const uint4*)(p + (size_t)32 * NN);                            \
        S2 = *(const uint4*)(p + (size_t)64 * NN);                            \
        S3 = *(const uint4*)(p + (size_t)96 * NN); }
#define DSWRITE(buf_) { unsigned char* bp = smem + (buf_) * 16384 + krow * 128 + wslot; \
        *(uint4*)(bp)         = S0;  *(uint4*)(bp + 4096)  = S1;              \
        *(uint4*)(bp + 8192)  = S2;  *(uint4*)(bp + 12288) = S3; }

        const int frow  = (l & 31) * 128;
        const int fslot = ((w * 2 + (l >> 5)) ^ (l & 7)) * 16;
        const int wdoff = w * 32 + (l >> 5) * 16;

        f32x16 a00 = {}, a01 = {}, a02 = {}, a03 = {}, a11 = {},
               a12 = {}, a13 = {}, a22 = {}, a23 = {}, a33 = {};
        float macc0 = 0.f, macc1 = 0.f, macc2 = 0.f, macc3 = 0.f;

        GLOAD(0);
        __syncthreads();
        DSWRITE(0);
        GLOAD(1);
        __syncthreads();

#pragma unroll 2
        for (int st = 0; st < NST; ++st) {
            const int cur = st & 1;
            if (st < NST - 1) {
                DSWRITE(cur ^ 1);
                if (st < NST - 2) GLOAD(st + 2);
            }
            const unsigned char* tb = smem + cur * 16384;
            const half8 wf = *(const half8*)(smem + 32768 + st * 128 + wdoff);
            const half8 df = *(const half8*)(smem + 34816 + st * 128 + wdoff);
            half8 f0 = *(const half8*)(tb +     0 + frow + fslot) * wf;
            half8 f1 = *(const half8*)(tb +  4096 + frow + fslot) * wf;
            half8 f2 = *(const half8*)(tb +  8192 + frow + fslot) * wf;
            half8 f3 = *(const half8*)(tb + 12288 + frow + fslot) * wf;
#pragma unroll
            for (int j = 0; j < 8; ++j) {
                const float dj = (float)df[j];
                macc0 = fmaf((float)f0[j], dj, macc0);
                macc1 = fmaf((float)f1[j], dj, macc1);
                macc2 = fmaf((float)f2[j], dj, macc2);
                macc3 = fmaf((float)f3[j], dj, macc3);
            }
            a00 = __builtin_amdgcn_mfma_f32_32x32x16_f16(f0, f0, a00, 0, 0, 0);
            a01 = __builtin_amdgcn_mfma_f32_32x32x16_f16(f0, f1, a01, 0, 0, 0);
            a02 = __builtin_amdgcn_mfma_f32_32x32x16_f16(f0, f2, a02, 0, 0, 0);
            a03 = __builtin_amdgcn_mfma_f32_32x32x16_f16(f0, f3, a03, 0, 0, 0);
            a11 = __builtin_amdgcn_mfma_f32_32x32x16_f16(f1, f1, a11, 0, 0, 0);
            a12 = __builtin_amdgcn_mfma_f32_32x32x16_f16(f1, f2, a12, 0, 0, 0);
            a13 = __builtin_amdgcn_mfma_f32_32x32x16_f16(f1, f3, a13, 0, 0, 0);
            a22 = __builtin_amdgcn_mfma_f32_32x32x16_f16(f2, f2, a22, 0, 0, 0);
            a23 = __builtin_amdgcn_mfma_f32_32x32x16_f16(f2, f3, a23, 0, 0, 0);
            a33 = __builtin_amdgcn_mfma_f32_32x32x16_f16(f3, f3, a33, 0, 0, 0);
            __syncthreads();
        }

        {
            float* M = (float*)(smem + 32768);
            const int base = (w * 2 + (l >> 5)) * 128 + (l & 31);
            M[base +  0] = macc0;  M[base + 32] = macc1;
            M[base + 64] = macc2;  M[base + 96] = macc3;
        }
        _Float16* Gp = (_Float16*)(ws + GP_OFF) + (size_t)(b * NCHUNK + chunk) * 10240;
        float* Mp = (float*)(ws + MP_OFF) + (size_t)(b * NCHUNK + chunk) * KK;
        float* R = (float*)smem;

#define PHASE(p_, A0_, A1_)                                                    \
    {                                                                          \
        *(f32x16*)(R + (w * 2 + 0) * 1024 + l * 16) = A0_;                     \
        *(f32x16*)(R + (w * 2 + 1) * 1024 + l * 16) = A1_;                     \
        __syncthreads();                                                       \
        _Pragma("unroll")                                                      \
        for (int pass = 0; pass < 2; ++pass) {                                 \
            const int e = pass * 1024 + tid * 4;                               \
            float4 s0 = *(float4*)(R + e);                                     \
            float4 s1 = *(float4*)(R + 2048 + e);                              \
            float4 s2 = *(float4*)(R + 4096 + e);                              \
            float4 s3 = *(float4*)(R + 6144 + e);                              \
            float sx = s0.x + s1.x + s2.x + s3.x;                              \
            float sy = s0.y + s1.y + s2.y + s3.y;                              \
            float sz = s0.z + s1.z + s2.z + s3.z;                              \
            float sw = s0.w + s1.w + s2.w + s3.w;                              \
            half4 h = { (_Float16)sx, (_Float16)sy, (_Float16)sz, (_Float16)sw }; \
            *(half4*)(Gp + (p_) * 2048 + e) = h;                               \
        }                                                                      \
        if ((p_) == 0 && tid < 128) {                                          \
            const float* M = (const float*)(smem + 32768);                     \
            float s = 0.f;                                                     \
            _Pragma("unroll")                                                  \
            for (int c8 = 0; c8 < 8; ++c8) s += M[c8 * 128 + tid];             \
            Mp[tid] = s;                                                       \
        }                                                                      \
        __syncthreads();                                                       \
    }

        PHASE(0, a00, a01)
        PHASE(1, a02, a03)
        PHASE(2, a11, a12)
        PHASE(3, a13, a22)
        PHASE(4, a23, a33)
#undef PHASE
#undef GLOAD
#undef DSWRITE
    }
}

// ---------------------------------------------------------------------------
// K2: reduce partial tiles -> G (identical work, wrapped in REP_RED).
// ---------------------------------------------------------------------------
__global__ __launch_bounds__(256) void reduce_kernel(
    const float* __restrict__ sig, unsigned char* __restrict__ ws0)
{
    const int tid = threadIdx.x;
    const int b  = blockIdx.x / 5;
    const int t2 = blockIdx.x % 5;

    const int e_local = tid * 8;
    const int tile = t2 * 2 + (e_local >> 10);
    const int off  = e_local & 1023;
    const int lane = off >> 4;
    const int r0   = off & 15;

    static const int TT[10] = {0,0,0,0,1,1,1,2,2,3};
    static const int UU[10] = {0,1,2,3,1,2,3,2,3,3};
    const int tt = TT[tile], uu = UU[tile];
    const int C = uu * 32 + (lane & 31);

#pragma unroll 1
    for (int rep = 0; rep < REP_RED; ++rep) {
        unsigned char* ws = ws0;  asm volatile("" : "+v"(ws));
        const _Float16* Gp = (const _Float16*)(ws + GP_OFF)
                           + (size_t)b * NCHUNK * 10240 + (size_t)t2 * 2048 + e_local;
        float s[8] = {0.f,0.f,0.f,0.f,0.f,0.f,0.f,0.f};
#pragma unroll
        for (int ch = 0; ch < NCHUNK; ++ch) {
            half8 v = *(const half8*)(Gp + (size_t)ch * 10240);
#pragma unroll
            for (int j = 0; j < 8; ++j) s[j] += (float)v[j];
        }

        float* G = (float*)(ws + G_OFF) + (size_t)b * 16384;
        const float sg = sig[0];
#pragma unroll
        for (int j = 0; j < 8; ++j) {
            const int reg = r0 + j;
            const int row = (reg & 3) + 8 * (reg >> 2) + 4 * (lane >> 5);
            const int Rr = tt * 32 + row;
            float v = s[j];
            G[Rr * KK + C] = (Rr == C) ? v + sg : v;
            if (tt != uu) G[C * KK + Rr] = v;
        }
    }
}

// ---------------------------------------------------------------------------
// K3: CG solve (identical work, wrapped in REP_SOLVE).
// ---------------------------------------------------------------------------
__device__ __forceinline__ float blockDot(float a, float bvl, float* red)
{
    float v = a * bvl;
#pragma unroll
    for (int off = 32; off > 0; off >>= 1) v += __shfl_down(v, off, 64);
    const int wid = threadIdx.x >> 6;
    if ((threadIdx.x & 63) == 0) red[wid] = v;
    __syncthreads();
    float s = red[0] + red[1];
    __syncthreads();
    return s;
}

__global__ __launch_bounds__(128, 1) void solve_kernel(
    const unsigned char* __restrict__ ws0, float* __restrict__ out)
{
    const int b = blockIdx.x;
    const int i = threadIdx.x;

    __shared__ float ps[KK];
    __shared__ float red[2];

#pragma unroll 1
    for (int rep = 0; rep < REP_SOLVE; ++rep) {
        const unsigned char* ws = ws0;  asm volatile("" : "+v"(ws));
        const float* G  = (const float*)(ws + G_OFF) + (size_t)b * 16384;
        const float* Mp = (const float*)(ws + MP_OFF) + (size_t)b * NCHUNK * KK;
        __syncthreads();          // ps reuse fence across reps

        float Gr[KK];
#pragma unroll
        for (int j = 0; j < KK; ++j) Gr[j] = G[j * KK + i];

        float mvv = 0.f;
#pragma unroll
        for (int ch = 0; ch < NCHUNK; ++ch) mvv += Mp[ch * KK + i];

        float x = 0.f, r = mvv, p = r;
        ps[i] = p;
        float rs = blockDot(r, r, red);

        for (int it = 0; it < NITER; ++it) {
            float q0 = 0.f, q1 = 0.f, q2 = 0.f, q3 = 0.f;
#pragma unroll
            for (int u = 0; u < 32; ++u) {
                float4 pv = *reinterpret_cast<const float4*>(&ps[4 * u]);
                q0 = fmaf(Gr[4 * u + 0], pv.x, q0);
                q1 = fmaf(Gr[4 * u + 1], pv.y, q1);
                q2 = fmaf(Gr[4 * u + 2], pv.z, q2);
                q3 = fmaf(Gr[4 * u + 3], pv.w, q3);
            }
            float q = (q0 + q1) + (q2 + q3);

            float pq    = blockDot(p, q, red);
            float alpha = rs / (pq + 1e-30f);
            x = fmaf(alpha, p, x);
            r = fmaf(-alpha, q, r);
            float rs2  = blockDot(r, r, red);
            float beta = rs2 / (rs + 1e-30f);
            rs = rs2;
            p  = fmaf(beta, p, r);
            ps[i] = p;
            __syncthreads();
        }
        out[(size_t)b * KK + i] = x;
    }
}

// ---------------------------------------------------------------------------
extern "C" void kernel_launch(void* const* d_in, const int* in_sizes, int n_in,
                              void* d_out, int out_size, void* d_ws, size_t ws_size,
                              hipStream_t stream)
{
    const float* data = (const float*)d_in[0];
    const float* mask = (const float*)d_in[1];
    const float* mult = (const float*)d_in[2];
    const float* sig  = (const float*)d_in[3];
    unsigned char* ws = (unsigned char*)d_ws;
    float* out = (float*)d_out;

    prep_kernel  <<<256, 256, 0, stream>>>(data, mask, mult, ws);
    gram_kernel  <<<BATCH * NCHUNK, 256, 0, stream>>>(ws);
    reduce_kernel<<<BATCH * 5, 256, 0, stream>>>(sig, ws);
    solve_kernel <<<BATCH, 128, 0, stream>>>(ws, out);
}

// Round 6
// 109.048 us; speedup vs baseline: 8.2676x; 8.2676x over previous
//
#include <hip/hip_runtime.h>

#define BATCH 8
#define NN 32768
#define KK 128
#define NCHUNK 32
#define CHUNK 1024            // NN / NCHUNK
#define NST 16                // super-tiles of 64 n per chunk
#define NITER 8               // CG iterations (kappa ~1.4)

typedef __attribute__((ext_vector_type(8)))  _Float16 half8;
typedef __attribute__((ext_vector_type(4)))  _Float16 half4;
typedef __attribute__((ext_vector_type(16))) float    f32x16;

// ---- workspace byte offsets ----
#define MT_OFF   0ull                      // multT fp16 [128][32768]
#define WH_OFF   (MT_OFF + 8388608ull)     // wh fp16 [8][32768]  (mask)
#define DH_OFF   (WH_OFF + 524288ull)      // dh fp16 [8][32768]  (data)
#define GP_OFF   (DH_OFF + 524288ull)      // Gp fp16 [8][32][10][1024] partial tiles
#define MP_OFF   (GP_OFF + 5242880ull)     // Mp f32  [8][32][128]

// ---------------------------------------------------------------------------
// K0: fused conv (mask/data -> fp16) + transpose (mult f32 [N][K] -> multT
// fp16 [K][N]).  Coalesced global writes; XOR-swizzled LDS staging.
// (unchanged from validated R4)
// ---------------------------------------------------------------------------
__global__ __launch_bounds__(256) void prep_kernel(
    const float* __restrict__ data, const float* __restrict__ mask,
    const float* __restrict__ mult, unsigned char* __restrict__ ws)
{
    __shared__ _Float16 t[128][136];
    const int tid = threadIdx.x;
    const int n0  = blockIdx.x * 128;

    {
        const int b = tid >> 5, q = tid & 31;
        const size_t src = (size_t)b * NN + n0 + q * 4;
        const float4 d4 = *(const float4*)(data + src);
        const float4 m4 = *(const float4*)(mask + src);
        half4 w = { (_Float16)m4.x, (_Float16)m4.y, (_Float16)m4.z, (_Float16)m4.w };
        half4 d = { (_Float16)d4.x, (_Float16)d4.y, (_Float16)d4.z, (_Float16)d4.w };
        *(half4*)((_Float16*)(ws + WH_OFF) + src) = w;
        *(half4*)((_Float16*)(ws + DH_OFF) + src) = d;
    }

    const float4* m4p = (const float4*)mult;
#pragma unroll
    for (int u = 0; u < 16; ++u) {
        const int c16 = u * 256 + tid;
        const int n  = c16 >> 5;
        const int kq = c16 & 31;
        float4 v = m4p[(size_t)(n0 + n) * 32 + kq];
        half4 h = { (_Float16)v.x, (_Float16)v.y, (_Float16)v.z, (_Float16)v.w };
        const int c4s = kq ^ ((n >> 3) & 7);
        *(half4*)&t[n][c4s * 4] = h;
    }
    __syncthreads();

    _Float16* mt = (_Float16*)(ws + MT_OFF);
    const int g = tid & 15;
#pragma unroll
    for (int i = 0; i < 8; ++i) {
        const int k = (tid >> 4) + i * 16;
        half8 v;
#pragma unroll
        for (int j = 0; j < 8; ++j) {
            const int n = g * 8 + j;
            const int cs = (k >> 2) ^ ((n >> 3) & 7);
            v[j] = t[n][cs * 4 + (k & 3)];
        }
        *(half8*)(mt + (size_t)k * NN + n0 + g * 8) = v;
    }
}

// ---------------------------------------------------------------------------
// K1: MFMA gram partials (upper-tri 10 tiles of 32x32) + m partials.
// (unchanged from validated R4)
// ---------------------------------------------------------------------------
__global__ __launch_bounds__(256, 1) void gram_kernel(
    unsigned char* __restrict__ ws)
{
    __shared__ unsigned char smem[36864];
    const int tid = threadIdx.x;
    const int b     = blockIdx.x >> 5;
    const int chunk = blockIdx.x & 31;
    const int n0    = chunk * CHUNK;
    const int w = tid >> 6, l = tid & 63;

    const _Float16* mt = (const _Float16*)(ws + MT_OFF);

    if (tid < 128) {
        half8 wv = *(const half8*)((const _Float16*)(ws + WH_OFF) + (size_t)b * NN + n0 + tid * 8);
        half8 dv = *(const half8*)((const _Float16*)(ws + DH_OFF) + (size_t)b * NN + n0 + tid * 8);
        *(half8*)(smem + 32768 + tid * 16) = wv;
        *(half8*)(smem + 34816 + tid * 16) = dv;
    }

    const int krow = tid >> 3;
    const int gd   = tid & 7;
    const _Float16* gsrc0 = mt + (size_t)krow * NN + n0 + gd * 8;
    const int wslot = (gd ^ (krow & 7)) * 16;

    uint4 S0, S1, S2, S3;
#define GLOAD(st_) { const _Float16* p = gsrc0 + (size_t)(st_) * 64;          \
        S0 = *(const uint4*)(p);                                              \
        S1 = *(const uint4*)(p + (size_t)32 * NN);                            \
        S2 = *(const uint4*)(p + (size_t)64 * NN);                            \
        S3 = *(const uint4*)(p + (size_t)96 * NN); }
#define DSWRITE(buf_) { unsigned char* bp = smem + (buf_) * 16384 + krow * 128 + wslot; \
        *(uint4*)(bp)         = S0;  *(uint4*)(bp + 4096)  = S1;              \
        *(uint4*)(bp + 8192)  = S2;  *(uint4*)(bp + 12288) = S3; }

    const int frow  = (l & 31) * 128;
    const int fslot = ((w * 2 + (l >> 5)) ^ (l & 7)) * 16;
    const int wdoff = w * 32 + (l >> 5) * 16;

    f32x16 a00 = {}, a01 = {}, a02 = {}, a03 = {}, a11 = {},
           a12 = {}, a13 = {}, a22 = {}, a23 = {}, a33 = {};
    float macc0 = 0.f, macc1 = 0.f, macc2 = 0.f, macc3 = 0.f;

    GLOAD(0);
    __syncthreads();
    DSWRITE(0);
    GLOAD(1);
    __syncthreads();

#pragma unroll 2
    for (int st = 0; st < NST; ++st) {
        const int cur = st & 1;
        if (st < NST - 1) {
            DSWRITE(cur ^ 1);
            if (st < NST - 2) GLOAD(st + 2);
        }
        const unsigned char* tb = smem + cur * 16384;
        const half8 wf = *(const half8*)(smem + 32768 + st * 128 + wdoff);
        const half8 df = *(const half8*)(smem + 34816 + st * 128 + wdoff);
        half8 f0 = *(const half8*)(tb +     0 + frow + fslot) * wf;
        half8 f1 = *(const half8*)(tb +  4096 + frow + fslot) * wf;
        half8 f2 = *(const half8*)(tb +  8192 + frow + fslot) * wf;
        half8 f3 = *(const half8*)(tb + 12288 + frow + fslot) * wf;
#pragma unroll
        for (int j = 0; j < 8; ++j) {
            const float dj = (float)df[j];
            macc0 = fmaf((float)f0[j], dj, macc0);
            macc1 = fmaf((float)f1[j], dj, macc1);
            macc2 = fmaf((float)f2[j], dj, macc2);
            macc3 = fmaf((float)f3[j], dj, macc3);
        }
        a00 = __builtin_amdgcn_mfma_f32_32x32x16_f16(f0, f0, a00, 0, 0, 0);
        a01 = __builtin_amdgcn_mfma_f32_32x32x16_f16(f0, f1, a01, 0, 0, 0);
        a02 = __builtin_amdgcn_mfma_f32_32x32x16_f16(f0, f2, a02, 0, 0, 0);
        a03 = __builtin_amdgcn_mfma_f32_32x32x16_f16(f0, f3, a03, 0, 0, 0);
        a11 = __builtin_amdgcn_mfma_f32_32x32x16_f16(f1, f1, a11, 0, 0, 0);
        a12 = __builtin_amdgcn_mfma_f32_32x32x16_f16(f1, f2, a12, 0, 0, 0);
        a13 = __builtin_amdgcn_mfma_f32_32x32x16_f16(f1, f3, a13, 0, 0, 0);
        a22 = __builtin_amdgcn_mfma_f32_32x32x16_f16(f2, f2, a22, 0, 0, 0);
        a23 = __builtin_amdgcn_mfma_f32_32x32x16_f16(f2, f3, a23, 0, 0, 0);
        a33 = __builtin_amdgcn_mfma_f32_32x32x16_f16(f3, f3, a33, 0, 0, 0);
        __syncthreads();
    }

    {
        float* M = (float*)(smem + 32768);
        const int base = (w * 2 + (l >> 5)) * 128 + (l & 31);
        M[base +  0] = macc0;  M[base + 32] = macc1;
        M[base + 64] = macc2;  M[base + 96] = macc3;
    }
    _Float16* Gp = (_Float16*)(ws + GP_OFF) + (size_t)(b * NCHUNK + chunk) * 10240;
    float* Mp = (float*)(ws + MP_OFF) + (size_t)(b * NCHUNK + chunk) * KK;
    float* R = (float*)smem;

#define PHASE(p_, A0_, A1_)                                                    \
    {                                                                          \
        *(f32x16*)(R + (w * 2 + 0) * 1024 + l * 16) = A0_;                     \
        *(f32x16*)(R + (w * 2 + 1) * 1024 + l * 16) = A1_;                     \
        __syncthreads();                                                       \
        _Pragma("unroll")                                                      \
        for (int pass = 0; pass < 2; ++pass) {                                 \
            const int e = pass * 1024 + tid * 4;                               \
            float4 s0 = *(float4*)(R + e);                                     \
            float4 s1 = *(float4*)(R + 2048 + e);                              \
            float4 s2 = *(float4*)(R + 4096 + e);                              \
            float4 s3 = *(float4*)(R + 6144 + e);                              \
            float sx = s0.x + s1.x + s2.x + s3.x;                              \
            float sy = s0.y + s1.y + s2.y + s3.y;                              \
            float sz = s0.z + s1.z + s2.z + s3.z;                              \
            float sw = s0.w + s1.w + s2.w + s3.w;                              \
            half4 h = { (_Float16)sx, (_Float16)sy, (_Float16)sz, (_Float16)sw }; \
            *(half4*)(Gp + (p_) * 2048 + e) = h;                               \
        }                                                                      \
        if ((p_) == 0 && tid < 128) {                                          \
            const float* M = (const float*)(smem + 32768);                     \
            float s = 0.f;                                                     \
            _Pragma("unroll")                                                  \
            for (int c8 = 0; c8 < 8; ++c8) s += M[c8 * 128 + tid];             \
            Mp[tid] = s;                                                       \
        }                                                                      \
        __syncthreads();                                                       \
    }

    PHASE(0, a00, a01)
    PHASE(1, a02, a03)
    PHASE(2, a11, a12)
    PHASE(3, a13, a22)
    PHASE(4, a23, a33)
#undef PHASE
#undef GLOAD
#undef DSWRITE
}

// ---------------------------------------------------------------------------
// K2: fused reduce + CG solve.  8 blocks (one per batch) x 256 threads.
// Phase A: sum fp16 partial tiles over chunks, decode C/D layout
//          (col=lane&31, row=(reg&3)+8*(reg>>2)+4*(lane>>5)), assemble full
//          G (+sigma^2 I) in LDS (64 KB).
// Phase B: CG.  Thread (i = tid&127, h = tid>>7) holds HALF a G-row:
//          Gr[64] = G[h*64+j][i] -> only 64 VGPRs, no scratch spill (the R5
//          measured 10.8us came from Gr[128] spilling at VGPR_Count=92).
//          Row state (x,r,p) duplicated across h; blockDots double-count
//          consistently so alpha/beta are unaffected.
// ---------------------------------------------------------------------------
__device__ __forceinline__ float blockDot4(float a, float bvl, float* red)
{
    float v = a * bvl;
#pragma unroll
    for (int off = 32; off > 0; off >>= 1) v += __shfl_down(v, off, 64);
    const int wid = threadIdx.x >> 6;
    if ((threadIdx.x & 63) == 0) red[wid] = v;
    __syncthreads();
    float s = (red[0] + red[1]) + (red[2] + red[3]);
    __syncthreads();
    return s;
}

__global__ __launch_bounds__(256, 1) void solve_kernel(
    const float* __restrict__ sig, const unsigned char* __restrict__ ws,
    float* __restrict__ out)
{
    __shared__ float Gl[KK * KK];      // 64 KB
    __shared__ float ps[KK];
    __shared__ float qex[256];
    __shared__ float red[4];

    const int tid = threadIdx.x;
    const int b   = blockIdx.x;
    const int i   = tid & 127;
    const int h   = tid >> 7;

    // ---- Phase A: assemble G in LDS ----
    static const int TT[10] = {0,0,0,0,1,1,1,2,2,3};
    static const int UU[10] = {0,1,2,3,1,2,3,2,3,3};
    const _Float16* Gp = (const _Float16*)(ws + GP_OFF) + (size_t)b * NCHUNK * 10240;
    const float sg = sig[0];
    const int lane = i >> 1;             // decode: off = i*8 -> lane = off>>4
    const int r0   = (i & 1) * 8;        //          r0 = off & 15
    const int C0   = lane & 31;
    const int rhi  = 4 * (lane >> 5);

#pragma unroll
    for (int gi = 0; gi < 5; ++gi) {
        const int e = (gi * 256 + tid) * 8;          // granule start elem
        float s[8] = {0.f,0.f,0.f,0.f,0.f,0.f,0.f,0.f};
        const _Float16* gp = Gp + e;
#pragma unroll
        for (int ch = 0; ch < NCHUNK; ++ch) {
            half8 v = *(const half8*)(gp + (size_t)ch * 10240);
#pragma unroll
            for (int j = 0; j < 8; ++j) s[j] += (float)v[j];
        }
        const int tile = gi * 2 + h;                 // = e >> 10
        const int tt = TT[tile], uu = UU[tile];
        const int C = uu * 32 + C0;
#pragma unroll
        for (int j = 0; j < 8; ++j) {
            const int reg = r0 + j;
            const int row = (reg & 3) + 8 * (reg >> 2) + rhi;
            const int Rr = tt * 32 + row;
            const float v = s[j];
            Gl[Rr * KK + C] = (Rr == C) ? v + sg : v;
            if (tt != uu) Gl[C * KK + Rr] = v;
        }
    }
    __syncthreads();

    // ---- Phase B: CG ----
    float Gr[64];
#pragma unroll
    for (int j = 0; j < 64; ++j) Gr[j] = Gl[(h * 64 + j) * KK + i];

    const float* Mp = (const float*)(ws + MP_OFF) + (size_t)b * NCHUNK * KK;
    float mvv = 0.f;
#pragma unroll
    for (int ch = 0; ch < NCHUNK; ++ch) mvv += Mp[ch * KK + i];

    float x = 0.f, r = mvv, p = r;
    ps[i] = p;                           // both halves write identical value
    float rs = blockDot4(r, r, red);     // internal barriers publish ps

    for (int it = 0; it < NITER; ++it) {
        float q0 = 0.f, q1 = 0.f, q2 = 0.f, q3 = 0.f;
        const float* psh = ps + h * 64;
#pragma unroll
        for (int u = 0; u < 16; ++u) {
            float4 pv = *(const float4*)(psh + 4 * u);
            q0 = fmaf(Gr[4 * u + 0], pv.x, q0);
            q1 = fmaf(Gr[4 * u + 1], pv.y, q1);
            q2 = fmaf(Gr[4 * u + 2], pv.z, q2);
            q3 = fmaf(Gr[4 * u + 3], pv.w, q3);
        }
        qex[tid] = (q0 + q1) + (q2 + q3);
        __syncthreads();
        const float q = qex[i] + qex[128 + i];

        float pq    = blockDot4(p, q, red);
        float alpha = rs / (pq + 1e-30f);
        x = fmaf(alpha, p, x);
        r = fmaf(-alpha, q, r);
        float rs2  = blockDot4(r, r, red);
        float beta = rs2 / (rs + 1e-30f);
        rs = rs2;
        p  = fmaf(beta, p, r);
        __syncthreads();                 // qex/ps consumers done
        ps[i] = p;
        __syncthreads();
    }
    if (h == 0) out[(size_t)b * KK + i] = x;
}

// ---------------------------------------------------------------------------
extern "C" void kernel_launch(void* const* d_in, const int* in_sizes, int n_in,
                              void* d_out, int out_size, void* d_ws, size_t ws_size,
                              hipStream_t stream)
{
    const float* data = (const float*)d_in[0];
    const float* mask = (const float*)d_in[1];
    const float* mult = (const float*)d_in[2];
    const float* sig  = (const float*)d_in[3];
    unsigned char* ws = (unsigned char*)d_ws;
    float* out = (float*)d_out;

    prep_kernel <<<256, 256, 0, stream>>>(data, mask, mult, ws);
    gram_kernel <<<BATCH * NCHUNK, 256, 0, stream>>>(ws);
    solve_kernel<<<BATCH, 256, 0, stream>>>(sig, ws, out);
}